// Round 5
// baseline (69.204 us; speedup 1.0000x reference)
//
#include <hip/hip_runtime.h>
#include <cstdint>
#include <cmath>

#define D_DIM 2048
#define E_DIM 64
#define N_TOK 16384
#define K_TOP 8
#define KSTEP 32
#define KSLICE 4      // K split across the block's 4 waves
#define TSTEPS 16     // k-steps per wave = 2048 / (32*4)
#define BLK_TOK 16    // tokens per block
#define NFRAG 12      // 4 etiles x 3 terms (h,m,l)

typedef __attribute__((ext_vector_type(8))) short bf16x8;
typedef __attribute__((ext_vector_type(4))) float f32x4;

union U4 { uint4 u; bf16x8 s; float4 f; };

// round-to-nearest bf16 3-way split: x = h + m + l + r, |r| ~ 2^-23 |x|
__device__ inline void split3_8(const float* a8, bf16x8& h, bf16x8& m, bf16x8& l) {
#pragma unroll
  for (int j = 0; j < 8; ++j) {
    const float x = a8[j];
    const unsigned u = __builtin_bit_cast(unsigned, x);
    const unsigned rh = (u + 0x7FFFu + ((u >> 16) & 1u)) & 0xFFFF0000u;
    h[j] = (short)(rh >> 16);
    const float r1 = x - __builtin_bit_cast(float, rh);
    const unsigned u1 = __builtin_bit_cast(unsigned, r1);
    const unsigned rm = (u1 + 0x7FFFu + ((u1 >> 16) & 1u)) & 0xFFFF0000u;
    m[j] = (short)(rm >> 16);
    const float r2 = r1 - __builtin_bit_cast(float, rm);
    l[j] = (short)(__builtin_bit_cast(unsigned, r2) >> 16);
  }
}

// Kernel 1: pre-split W [64][2048] into 3-term MFMA B-fragments in d_ws.
// WF[(ks*12 + et*3 + term)*64 + lane]; lane holds W[et*16+(l&15)][ks*32+(l>>4)*8+j]
__global__ void wprep_kernel(const float* __restrict__ W, uint4* __restrict__ WF) {
  const int gid = blockIdx.x * 256 + threadIdx.x;  // 16384 = 64ks * 4et * 64lane
  const int lane = gid & 63;
  const int et = (gid >> 6) & 3;
  const int ks = gid >> 8;
  const int e = et * 16 + (lane & 15);
  const int kg = lane >> 4;
  const float* src = W + (size_t)e * D_DIM + ks * KSTEP + kg * 8;
  const float4 a = ((const float4*)src)[0];
  const float4 b = ((const float4*)src)[1];
  float a8[8] = {a.x, a.y, a.z, a.w, b.x, b.y, b.z, b.w};
  U4 h, m, l;
  split3_8(a8, h.s, m.s, l.s);
  const int fbase = (ks * NFRAG + et * 3) * 64 + lane;
  WF[fbase] = h.u;
  WF[fbase + 64] = m.u;
  WF[fbase + 128] = l.u;
}

struct Frag { U4 a0, a1; uint4 b[NFRAG]; };

// Kernel 2: barrier-free register-pipelined GEMM + K-split reduce + top-8 epilogue.
__global__ __launch_bounds__(256)
void gemm_router(const float* __restrict__ X, const uint4* __restrict__ WF,
                 float* __restrict__ Pout, float* __restrict__ Mout) {
  __shared__ float red[KSLICE - 1][64][17];  // stride-17: conflict-free scalar access

  const int tid = threadIdx.x;
  const int w = tid >> 6;   // k-slice id 0..3
  const int l = tid & 63;
  const int col = l & 15;   // token-within-tile (A row) / expert-within-etile (C col)
  const int kg = l >> 4;
  const int tok0 = blockIdx.x * BLK_TOK;

  // per-wave global bases (k-slice w covers ks = w*16 .. w*16+15)
  const float* gX = X + (size_t)(tok0 + col) * D_DIM + (size_t)w * TSTEPS * KSTEP + kg * 8;
  const uint4* gB = WF + (size_t)w * TSTEPS * (NFRAG * 64) + l;

  f32x4 acc0[4], acc1[4];
#pragma unroll
  for (int et = 0; et < 4; ++et) { acc0[et] = (f32x4)0.f; acc1[et] = (f32x4)0.f; }

  auto loadstep = [&](int t, Frag& f) {
    const float* a = gX + t * KSTEP;
    f.a0.f = *(const float4*)a;
    f.a1.f = *(const float4*)(a + 4);
    const uint4* b = gB + (size_t)t * (NFRAG * 64);
#pragma unroll
    for (int i = 0; i < NFRAG; ++i) f.b[i] = b[i * 64];
  };

  auto crunch = [&](Frag& f) {
    float a8[8] = {f.a0.f.x, f.a0.f.y, f.a0.f.z, f.a0.f.w,
                   f.a1.f.x, f.a1.f.y, f.a1.f.z, f.a1.f.w};
    bf16x8 ah, am, al;
    split3_8(a8, ah, am, al);
    U4 bh[4], bm[4], bl[4];
#pragma unroll
    for (int et = 0; et < 4; ++et) {
      bh[et].u = f.b[et * 3 + 0];
      bm[et].u = f.b[et * 3 + 1];
      bl[et].u = f.b[et * 3 + 2];
    }
#pragma unroll
    for (int et = 0; et < 4; ++et)
      acc0[et] = __builtin_amdgcn_mfma_f32_16x16x32_bf16(ah, bh[et].s, acc0[et], 0, 0, 0);
#pragma unroll
    for (int et = 0; et < 4; ++et)
      acc1[et] = __builtin_amdgcn_mfma_f32_16x16x32_bf16(ah, bm[et].s, acc1[et], 0, 0, 0);
#pragma unroll
    for (int et = 0; et < 4; ++et)
      acc1[et] = __builtin_amdgcn_mfma_f32_16x16x32_bf16(am, bh[et].s, acc1[et], 0, 0, 0);
#pragma unroll
    for (int et = 0; et < 4; ++et)
      acc1[et] = __builtin_amdgcn_mfma_f32_16x16x32_bf16(ah, bl[et].s, acc1[et], 0, 0, 0);
#pragma unroll
    for (int et = 0; et < 4; ++et)
      acc1[et] = __builtin_amdgcn_mfma_f32_16x16x32_bf16(al, bh[et].s, acc1[et], 0, 0, 0);
#pragma unroll
    for (int et = 0; et < 4; ++et)
      acc1[et] = __builtin_amdgcn_mfma_f32_16x16x32_bf16(am, bm[et].s, acc1[et], 0, 0, 0);
  };

  // register double-buffered, barrier-free main loop (TSTEPS even)
  Frag fA, fB;
  loadstep(0, fA);
  for (int t = 0; t < TSTEPS; t += 2) {
    loadstep(t + 1, fB);                       // t+1 <= 15 always
    crunch(fA);
    if (t + 2 < TSTEPS) loadstep(t + 2, fA);
    crunch(fB);
  }

  // fold the two accumulators -> 16 floats per lane [et][q]
  float fin[16];
#pragma unroll
  for (int et = 0; et < 4; ++et)
#pragma unroll
    for (int q = 0; q < 4; ++q)
      fin[et * 4 + q] = acc0[et][q] + acc1[et][q];

  // cross-wave K-slice reduction via LDS (one barrier total)
  if (w > 0) {
#pragma unroll
    for (int i = 0; i < 16; ++i) red[w - 1][l][i] = fin[i];
  }
  __syncthreads();
  if (w != 0) return;

#pragma unroll
  for (int j = 0; j < KSLICE - 1; ++j)
#pragma unroll
    for (int i = 0; i < 16; ++i) fin[i] += red[j][l][i];

  // epilogue (wave 0): C/D layout col=lane&15, row=(lane>>4)*4+reg (HW-verified)
#pragma unroll
  for (int q = 0; q < 4; ++q) {
    float v[4];
#pragma unroll
    for (int et = 0; et < 4; ++et) v[et] = fin[et * 4 + q];

    float topv[K_TOP];
    int topi[K_TOP];
#pragma unroll
    for (int t = 0; t < K_TOP; ++t) {
      float bv = v[0];
      int bi = col;
#pragma unroll
      for (int et = 1; et < 4; ++et) {
        const bool take = v[et] > bv;
        bv = take ? v[et] : bv;
        bi = take ? (et * 16 + col) : bi;
      }
#pragma unroll
      for (int off = 1; off < 16; off <<= 1) {
        const float ov = __shfl_xor(bv, off, 64);
        const int oi = __shfl_xor(bi, off, 64);
        const bool take = (ov > bv) || (ov == bv && oi < bi);  // lowest idx on tie
        bv = take ? ov : bv;
        bi = take ? oi : bi;
      }
      topv[t] = bv;
      topi[t] = bi;
#pragma unroll
      for (int et = 0; et < 4; ++et)
        if (bi == et * 16 + col) v[et] = -INFINITY;
    }

    float p[K_TOP], sum = 0.f;
#pragma unroll
    for (int t = 0; t < K_TOP; ++t) {
      p[t] = expf(topv[t] - topv[0]);
      sum += p[t];
    }
    const float inv = 1.f / sum;

    const int tok = tok0 + kg * 4 + q;
#pragma unroll
    for (int et = 0; et < 4; ++et) {
      const int e = et * 16 + col;
      float pv = 0.f, mv = 0.f;
#pragma unroll
      for (int t = 0; t < K_TOP; ++t) {
        const bool hit = (topi[t] == e);
        pv = hit ? p[t] * inv : pv;
        mv = hit ? 1.f : mv;
      }
      Pout[(size_t)tok * E_DIM + e] = pv;
      Mout[(size_t)tok * E_DIM + e] = mv;
    }
  }
}

extern "C" void kernel_launch(void* const* d_in, const int* in_sizes, int n_in,
                              void* d_out, int out_size, void* d_ws, size_t ws_size,
                              hipStream_t stream) {
  const float* X = (const float*)d_in[0];
  const float* W = (const float*)d_in[1];
  float* P = (float*)d_out;
  float* M = P + (size_t)N_TOK * E_DIM;
  uint4* WF = (uint4*)d_ws;  // 64 * 12 * 64 * 16B = 768 KB

  wprep_kernel<<<dim3(64), dim3(256), 0, stream>>>(W, WF);
  gemm_router<<<dim3(N_TOK / BLK_TOK), dim3(256), 0, stream>>>(X, WF, P, M);
}

// Round 6
// 55.247 us; speedup vs baseline: 1.2526x; 1.2526x over previous
//
#include <hip/hip_runtime.h>
#include <cstdint>
#include <cmath>

#define D_DIM 2048
#define E_DIM 64
#define N_TOK 16384
#define K_TOP 8
#define KSTEP 32
#define KSLICE 4       // K split across the block's 4 waves
#define TSTEPS 16      // k-steps per wave = 2048 / (32*4)
#define BLK_TOK 32     // tokens per block: 2 mtiles x 16
#define NFRAG 12       // 4 etiles x 3 terms (h,m,l)

typedef __attribute__((ext_vector_type(8))) short bf16x8;
typedef __attribute__((ext_vector_type(4))) float f32x4;

union U4 { uint4 u; bf16x8 s; };

// round-to-nearest bf16 3-way split: x = h + m + l + r, |r| ~ 2^-23 |x|
__device__ inline void split3_8(const float* a8, bf16x8& h, bf16x8& m, bf16x8& l) {
#pragma unroll
  for (int j = 0; j < 8; ++j) {
    const float x = a8[j];
    const unsigned u = __builtin_bit_cast(unsigned, x);
    const unsigned rh = (u + 0x7FFFu + ((u >> 16) & 1u)) & 0xFFFF0000u;
    h[j] = (short)(rh >> 16);
    const float r1 = x - __builtin_bit_cast(float, rh);
    const unsigned u1 = __builtin_bit_cast(unsigned, r1);
    const unsigned rm = (u1 + 0x7FFFu + ((u1 >> 16) & 1u)) & 0xFFFF0000u;
    m[j] = (short)(rm >> 16);
    const float r2 = r1 - __builtin_bit_cast(float, rm);
    l[j] = (short)(__builtin_bit_cast(unsigned, r2) >> 16);
  }
}

// Kernel 1: pre-split W [64][2048] into 3-term MFMA B-fragments in d_ws.
// WF[(ks*12 + et*3 + term)*64 + lane]; lane holds W[et*16+(l&15)][ks*32+(l>>4)*8+j]
__global__ void wprep_kernel(const float* __restrict__ W, uint4* __restrict__ WF) {
  const int gid = blockIdx.x * 256 + threadIdx.x;  // 16384 = 64ks * 4et * 64lane
  const int lane = gid & 63;
  const int et = (gid >> 6) & 3;
  const int ks = gid >> 8;
  const int e = et * 16 + (lane & 15);
  const int kg = lane >> 4;
  const float* src = W + (size_t)e * D_DIM + ks * KSTEP + kg * 8;
  const float4 a = ((const float4*)src)[0];
  const float4 b = ((const float4*)src)[1];
  float a8[8] = {a.x, a.y, a.z, a.w, b.x, b.y, b.z, b.w};
  U4 h, m, l;
  split3_8(a8, h.s, m.s, l.s);
  const int fbase = (ks * NFRAG + et * 3) * 64 + lane;
  WF[fbase] = h.u;
  WF[fbase + 64] = m.u;
  WF[fbase + 128] = l.u;
}

#define BCV(x) __builtin_bit_cast(bf16x8, x)
#define MM(d, A, B) d = __builtin_amdgcn_mfma_f32_16x16x32_bf16(A, BCV(B), d, 0, 0, 0)

// split two float4 (8 fp32) into 3 bf16x8 terms — all scalars, SROA-safe
#define SPLIT3V(v0, v1, H, M, L)                                     \
  do {                                                               \
    float a8_[8] = {v0.x, v0.y, v0.z, v0.w, v1.x, v1.y, v1.z, v1.w}; \
    split3_8(a8_, H, M, L);                                          \
  } while (0)

// Kernel 2: barrier-free register-pipelined GEMM (M=32/wave, K-split x4)
// + LDS K-reduce + top-8 softmax epilogue. NO structs, NO by-ref lambdas.
__global__ __launch_bounds__(256, 2)
void gemm_router(const float* __restrict__ X, const uint4* __restrict__ WF,
                 float* __restrict__ Pout, float* __restrict__ Mout) {
  __shared__ float red[2][KSLICE][64][17];  // 34.8 KB, stride-17 conflict-free

  const int tid = threadIdx.x;
  const int w = tid >> 6;   // k-slice 0..3
  const int l = tid & 63;
  const int col = l & 15;
  const int kg = l >> 4;
  const int tok0 = blockIdx.x * BLK_TOK;

  const float* gX0 = X + (size_t)(tok0 + col) * D_DIM + w * (TSTEPS * KSTEP) + kg * 8;
  const float* gX1 = gX0 + (size_t)16 * D_DIM;  // second mtile
  const uint4* gB = WF + (size_t)w * TSTEPS * (NFRAG * 64) + l;

  f32x4 acc0[8], acc1[8];  // [mt*4+et]; hh in acc0, the 5 cross terms in acc1
#pragma unroll
  for (int i = 0; i < 8; ++i) { acc0[i] = (f32x4)0.f; acc1[i] = (f32x4)0.f; }

  float4 xa00, xa01, xa10, xa11;  // X buffer A (even steps)
  float4 xb00, xb01, xb10, xb11;  // X buffer B (odd steps)
  uint4 bh[4], bm[4], bl[4];      // current-step B frags (constant-indexed)

#define LOAD_XA(t)                                    \
  do {                                                \
    const float* p0_ = gX0 + (t) * KSTEP;             \
    const float* p1_ = gX1 + (t) * KSTEP;             \
    xa00 = *(const float4*)p0_;                       \
    xa01 = *(const float4*)(p0_ + 4);                 \
    xa10 = *(const float4*)p1_;                       \
    xa11 = *(const float4*)(p1_ + 4);                 \
  } while (0)

#define LOAD_XB(t)                                    \
  do {                                                \
    const float* p0_ = gX0 + (t) * KSTEP;             \
    const float* p1_ = gX1 + (t) * KSTEP;             \
    xb00 = *(const float4*)p0_;                       \
    xb01 = *(const float4*)(p0_ + 4);                 \
    xb10 = *(const float4*)p1_;                       \
    xb11 = *(const float4*)(p1_ + 4);                 \
  } while (0)

#define LOAD_B(t)                                     \
  do {                                                \
    const uint4* bp_ = gB + (size_t)(t) * (NFRAG * 64); \
    bh[0] = bp_[0 * 64];  bm[0] = bp_[1 * 64];  bl[0] = bp_[2 * 64];  \
    bh[1] = bp_[3 * 64];  bm[1] = bp_[4 * 64];  bl[1] = bp_[5 * 64];  \
    bh[2] = bp_[6 * 64];  bm[2] = bp_[7 * 64];  bl[2] = bp_[8 * 64];  \
    bh[3] = bp_[9 * 64];  bm[3] = bp_[10 * 64]; bl[3] = bp_[11 * 64]; \
  } while (0)

  // 48 MFMAs for one step given split A terms for both mtiles
#define CRUNCH(AH0, AM0, AL0, AH1, AM1, AL1)                               \
  do {                                                                     \
    _Pragma("unroll") for (int et = 0; et < 4; ++et) MM(acc0[et], AH0, bh[et]);      \
    _Pragma("unroll") for (int et = 0; et < 4; ++et) MM(acc0[4 + et], AH1, bh[et]);  \
    _Pragma("unroll") for (int et = 0; et < 4; ++et) MM(acc1[et], AH0, bm[et]);      \
    _Pragma("unroll") for (int et = 0; et < 4; ++et) MM(acc1[4 + et], AH1, bm[et]);  \
    _Pragma("unroll") for (int et = 0; et < 4; ++et) MM(acc1[et], AM0, bh[et]);      \
    _Pragma("unroll") for (int et = 0; et < 4; ++et) MM(acc1[4 + et], AM1, bh[et]);  \
    _Pragma("unroll") for (int et = 0; et < 4; ++et) MM(acc1[et], AH0, bl[et]);      \
    _Pragma("unroll") for (int et = 0; et < 4; ++et) MM(acc1[4 + et], AH1, bl[et]);  \
    _Pragma("unroll") for (int et = 0; et < 4; ++et) MM(acc1[et], AL0, bh[et]);      \
    _Pragma("unroll") for (int et = 0; et < 4; ++et) MM(acc1[4 + et], AL1, bh[et]);  \
    _Pragma("unroll") for (int et = 0; et < 4; ++et) MM(acc1[et], AM0, bm[et]);      \
    _Pragma("unroll") for (int et = 0; et < 4; ++et) MM(acc1[4 + et], AM1, bm[et]);  \
  } while (0)

  LOAD_XA(0);
  LOAD_XB(1);

#pragma unroll 1
  for (int t = 0; t < TSTEPS; t += 2) {
    // even step t: consume buffer A
    {
      LOAD_B(t);
      bf16x8 ah0, am0, al0, ah1, am1, al1;
      SPLIT3V(xa00, xa01, ah0, am0, al0);  // ~300 VALU cyc, covers B's L2 latency
      SPLIT3V(xa10, xa11, ah1, am1, al1);
      if (t + 2 < TSTEPS) LOAD_XA(t + 2);  // X prefetch, 2-step lead
      CRUNCH(ah0, am0, al0, ah1, am1, al1);
    }
    // odd step t+1: consume buffer B
    {
      LOAD_B(t + 1);
      bf16x8 ah0, am0, al0, ah1, am1, al1;
      SPLIT3V(xb00, xb01, ah0, am0, al0);
      SPLIT3V(xb10, xb11, ah1, am1, al1);
      if (t + 3 < TSTEPS) LOAD_XB(t + 3);
      CRUNCH(ah0, am0, al0, ah1, am1, al1);
    }
  }

  // fold accumulators, write partials for both mtiles
#pragma unroll
  for (int mt = 0; mt < 2; ++mt)
#pragma unroll
    for (int et = 0; et < 4; ++et)
#pragma unroll
      for (int q = 0; q < 4; ++q)
        red[mt][w][l][et * 4 + q] = acc0[mt * 4 + et][q] + acc1[mt * 4 + et][q];

  __syncthreads();
  if (w >= 2) return;

  // wave w finalizes mtile w: sum 4 k-slice partials (fixed order -> deterministic)
  float fin[16];
#pragma unroll
  for (int i = 0; i < 16; ++i) {
    float s = red[w][0][l][i];
    s += red[w][1][l][i];
    s += red[w][2][l][i];
    s += red[w][3][l][i];
    fin[i] = s;
  }

  // epilogue: C/D layout col=lane&15, row=(lane>>4)*4+reg (HW-verified)
#pragma unroll
  for (int q = 0; q < 4; ++q) {
    float v[4];
#pragma unroll
    for (int et = 0; et < 4; ++et) v[et] = fin[et * 4 + q];

    float topv[K_TOP];
    int topi[K_TOP];
#pragma unroll
    for (int t = 0; t < K_TOP; ++t) {
      float bv = v[0];
      int bi = col;
#pragma unroll
      for (int et = 1; et < 4; ++et) {
        const bool take = v[et] > bv;
        bv = take ? v[et] : bv;
        bi = take ? (et * 16 + col) : bi;
      }
#pragma unroll
      for (int off = 1; off < 16; off <<= 1) {
        const float ov = __shfl_xor(bv, off, 64);
        const int oi = __shfl_xor(bi, off, 64);
        const bool take = (ov > bv) || (ov == bv && oi < bi);  // lowest idx on tie
        bv = take ? ov : bv;
        bi = take ? oi : bi;
      }
      topv[t] = bv;
      topi[t] = bi;
#pragma unroll
      for (int et = 0; et < 4; ++et)
        if (bi == et * 16 + col) v[et] = -INFINITY;
    }

    float p[K_TOP], sum = 0.f;
#pragma unroll
    for (int t = 0; t < K_TOP; ++t) {
      p[t] = expf(topv[t] - topv[0]);
      sum += p[t];
    }
    const float inv = 1.f / sum;

    const int tok = tok0 + w * 16 + kg * 4 + q;
#pragma unroll
    for (int et = 0; et < 4; ++et) {
      const int e = et * 16 + col;
      float pv = 0.f, mv = 0.f;
#pragma unroll
      for (int t = 0; t < K_TOP; ++t) {
        const bool hit = (topi[t] == e);
        pv = hit ? p[t] * inv : pv;
        mv = hit ? 1.f : mv;
      }
      Pout[(size_t)tok * E_DIM + e] = pv;
      Mout[(size_t)tok * E_DIM + e] = mv;
    }
  }
}

extern "C" void kernel_launch(void* const* d_in, const int* in_sizes, int n_in,
                              void* d_out, int out_size, void* d_ws, size_t ws_size,
                              hipStream_t stream) {
  const float* X = (const float*)d_in[0];
  const float* W = (const float*)d_in[1];
  float* P = (float*)d_out;
  float* M = P + (size_t)N_TOK * E_DIM;
  uint4* WF = (uint4*)d_ws;  // 64 * 12 * 64 * 16B = 768 KB

  wprep_kernel<<<dim3(64), dim3(256), 0, stream>>>(W, WF);
  gemm_router<<<dim3(N_TOK / BLK_TOK), dim3(256), 0, stream>>>(X, WF, P, M);
}